// Round 1
// baseline (302.658 us; speedup 1.0000x reference)
//
#include <hip/hip_runtime.h>
#include <stdint.h>

// ---------------------------------------------------------------------------
// SelfAttention: B=4, S=2048, E=1024 (single head)
//   q = Xq @ Wq^T ; k = Xk @ Wk^T ; vT = Wv @ Xv^T     (merged: 1 dispatch)
//   P = exp(q k^T / 32)  (fp32-safe, no max-sub; rowsums via epilogue atomics)
//   out = (P @ v) / rowsum
// R9 change: proj + scores ported to the 256^2 8-phase schedule
// (T2 XOR-swizzle + T3/T4 counted vmcnt + T5 setprio, m201 template).
// pv stays on the 128^2 body: at 256^2 it would be 128 blocks on 256 CUs.
// ---------------------------------------------------------------------------

typedef __attribute__((ext_vector_type(8))) short short8;       // 8 x bf16 frag
typedef __attribute__((ext_vector_type(4))) float floatx4;      // MFMA acc
typedef __attribute__((ext_vector_type(4))) unsigned short u16x4;
typedef __attribute__((ext_vector_type(4))) float f32x4v;

__device__ __forceinline__ unsigned short f32_to_bf16(float f) {
    union { float f; unsigned u; } c; c.f = f;
    unsigned u = c.u;
    return (unsigned short)((u + 0x7fffu + ((u >> 16) & 1u)) >> 16);  // RNE
}

#define G2L(g, l) __builtin_amdgcn_global_load_lds( \
    (__attribute__((address_space(1))) void*)(void*)(g), \
    (__attribute__((address_space(3))) void*)(l), 16, 0, 0)

#define BAR() __builtin_amdgcn_s_barrier()

// ---- merged fp32->bf16 converts (3x input, 3x weight) + rowsum zero ------
__global__ __launch_bounds__(256) void cvt_all(
    const float* __restrict__ q, const float* __restrict__ k,
    const float* __restrict__ v, const float* __restrict__ wq,
    const float* __restrict__ wk, const float* __restrict__ wv,
    unsigned short* __restrict__ Xq, unsigned short* __restrict__ Xk,
    unsigned short* __restrict__ Xv, unsigned short* __restrict__ Wq,
    unsigned short* __restrict__ Wk, unsigned short* __restrict__ Wv,
    float* __restrict__ rowsum) {
    const long NTE4 = 2097152;  // 8192*1024/4
    const long NW4  = 262144;   // 1024*1024/4
    long i = (long)blockIdx.x * 256 + threadIdx.x;
    const float* src;
    unsigned short* dst;
    long j;
    if (i < 3 * NTE4) {
        int a = (int)(i / NTE4); j = i - (long)a * NTE4;
        src = a == 0 ? q : a == 1 ? k : v;
        dst = a == 0 ? Xq : a == 1 ? Xk : Xv;
    } else {
        i -= 3 * NTE4;
        if (i < 3 * NW4) {
            int a = (int)(i / NW4); j = i - (long)a * NW4;
            src = a == 0 ? wq : a == 1 ? wk : wv;
            dst = a == 0 ? Wq : a == 1 ? Wk : Wv;
        } else {
            i -= 3 * NW4;           // 2048 groups -> rowsum[0..8191] = 0
            ((f32x4v*)rowsum)[i] = (f32x4v)0.0f;
            return;
        }
    }
    f32x4v f = ((const f32x4v*)src)[j];
    u16x4 o;
#pragma unroll
    for (int t = 0; t < 4; ++t) o[t] = f32_to_bf16(f[t]);
    ((u16x4*)dst)[j] = o;
}

// ===========================================================================
// OLD 128x128 body (kept for pv: 512 blocks, 4 blocks/CU co-resident)
// ===========================================================================
#define BM 128
#define BN 128
#define BK 64

template <int EPI>
__device__ __forceinline__ void gemm_body(
    const unsigned short* __restrict__ A, const unsigned short* __restrict__ B,
    void* __restrict__ Cv, int lda, int ldb, int ldc, int K, float scale,
    float* __restrict__ rowsum, int m0, int n0) {
    __shared__ unsigned short As[BM * BK];
    __shared__ unsigned short Bs[BN * BK];

    const int tid  = threadIdx.x;
    const int wave = tid >> 6;
    const int lane = tid & 63;
    const int lm   = lane & 15;
    const int quad = lane >> 4;
    const int wm   = wave >> 1;
    const int wn   = wave & 1;

    const int srow8 = lane >> 3;
    const int gcol  = ((lane & 7) ^ srow8) * 8;

    floatx4 acc[4][4];
#pragma unroll
    for (int i = 0; i < 4; ++i)
#pragma unroll
        for (int j = 0; j < 4; ++j) acc[i][j] = (floatx4)0.0f;

    for (int k0 = 0; k0 < K; k0 += BK) {
#pragma unroll
        for (int i = 0; i < 4; ++i) {
            const int rbase = wave * 32 + i * 8;
            G2L(A + (size_t)(m0 + rbase + srow8) * lda + k0 + gcol,
                &As[rbase * BK]);
            G2L(B + (size_t)(n0 + rbase + srow8) * ldb + k0 + gcol,
                &Bs[rbase * BK]);
        }
        __syncthreads();

#pragma unroll
        for (int s = 0; s < 2; ++s) {
            short8 af[4], bf[4];
#pragma unroll
            for (int t = 0; t < 4; ++t) {
                const int cs = ((s * 4 + quad) ^ (lm & 7)) * 8;
                af[t] = *(const short8*)&As[(wm * 64 + t * 16 + lm) * BK + cs];
                bf[t] = *(const short8*)&Bs[(wn * 64 + t * 16 + lm) * BK + cs];
            }
#pragma unroll
            for (int mt = 0; mt < 4; ++mt)
#pragma unroll
                for (int nt = 0; nt < 4; ++nt)
                    acc[mt][nt] = __builtin_amdgcn_mfma_f32_16x16x32_bf16(
                        af[mt], bf[nt], acc[mt][nt], 0, 0, 0);
        }
        __syncthreads();
    }

    if constexpr (EPI == 2) {
        float* C = (float*)Cv;
#pragma unroll
        for (int mt = 0; mt < 4; ++mt)
#pragma unroll
            for (int r = 0; r < 4; ++r) {
                const int row = m0 + wm * 64 + mt * 16 + quad * 4 + r;
                const float inv = 1.0f / rowsum[row];
#pragma unroll
                for (int nt = 0; nt < 4; ++nt) {
                    const int col = n0 + wn * 64 + nt * 16 + lm;
                    C[(size_t)row * ldc + col] = acc[mt][nt][r] * inv;
                }
            }
    }
}

__global__ __launch_bounds__(256, 4) void pv_kernel(
    const unsigned short* __restrict__ Sc, const unsigned short* __restrict__ vT,
    float* __restrict__ out, float* __restrict__ rowsum) {
    const long z = blockIdx.z;
    gemm_body<2>(Sc + z * 2048 * 2048, vT + z * 2048,
                 out + z * 2048 * 1024, 2048, 8192, 1024, 2048,
                 1.0f, rowsum + z * 2048,
                 blockIdx.x * BM, blockIdx.y * BN);
}

// ===========================================================================
// NEW 256x256 8-phase body (m201 template, plain HIP)
//   512 thr = 8 waves (2M x 4N), per-wave C = 128x64, BK=64, LDS 128 KiB.
//   Per K-tile: 4 phases, quadrant gray-code (m0,n0)(m1,n0)(m1,n1)(m0,n1)
//   so each phase reloads ONE operand half (12/8/4/0 ds_read_b128).
//   Staging (counted vmcnt, never 0 in steady state):
//     P1 -> (t+1).B-half0 [buf^1]   P2 -> (t+1).B-half1 [buf^1]
//     P3 -> (t+2).A-half0 [buf]     P4 -> (t+2).A-half1 [buf]
//   Each stage targets a region whose last ds_read was >=1 barrier earlier.
//   End-of-tile s_waitcnt vmcnt(4) => tile t+1 fully landed (drain 4 -> 0).
// ===========================================================================
template <int EPI>
__device__ __forceinline__ void gemm256_body(
    const unsigned short* __restrict__ A, const unsigned short* __restrict__ B,
    void* __restrict__ Cv, int lda, int ldb, int ldc, int K, float scale,
    float* __restrict__ rowsum, int m0, int n0) {
    __shared__ unsigned short As[2][256 * 64];
    __shared__ unsigned short Bs[2][256 * 64];

    const int tid   = threadIdx.x;
    const int wave  = tid >> 6;      // 0..7
    const int lane  = tid & 63;
    const int lm    = lane & 15;     // MFMA row-in-frag
    const int quad  = lane >> 4;     // 0..3
    const int wm    = wave >> 2;     // 0..1  (wave tile 2x4)
    const int wn    = wave & 3;      // 0..3
    const int srow8 = lane >> 3;
    const int gcol  = ((lane & 7) ^ srow8) * 8;  // pre-swizzled global col
    const int KT    = K >> 6;

#define STAGE_A(buf, half, kcol) do { \
        const int r0_ = (half) * 128 + wave * 8; \
        G2L(A + (size_t)(m0 + r0_ + srow8) * lda + (kcol) + gcol, \
            &As[buf][r0_ * 64]); \
        G2L(A + (size_t)(m0 + r0_ + 64 + srow8) * lda + (kcol) + gcol, \
            &As[buf][(r0_ + 64) * 64]); \
    } while (0)
#define STAGE_B(buf, half, kcol) do { \
        const int r0_ = (half) * 128 + wave * 8; \
        G2L(B + (size_t)(n0 + r0_ + srow8) * ldb + (kcol) + gcol, \
            &Bs[buf][r0_ * 64]); \
        G2L(B + (size_t)(n0 + r0_ + 64 + srow8) * ldb + (kcol) + gcol, \
            &Bs[buf][(r0_ + 64) * 64]); \
    } while (0)

    floatx4 acc[8][4];
#pragma unroll
    for (int i = 0; i < 8; ++i)
#pragma unroll
        for (int j = 0; j < 4; ++j) acc[i][j] = (floatx4)0.0f;

    // prologue: tile0 fully + tile1 A-halves; vmcnt(4) => tile0 landed
    STAGE_A(0, 0, 0); STAGE_A(0, 1, 0);
    STAGE_B(0, 0, 0); STAGE_B(0, 1, 0);
    STAGE_A(1, 0, 64); STAGE_A(1, 1, 64);
    asm volatile("s_waitcnt vmcnt(4)" ::: "memory");
    BAR();

    short8 aA[2][4];   // A half m0, lives P1..P4
    short8 aM[2][4];   // A half m1, lives P2..P3
    short8 bB[2][2];   // B half (reloaded at P3)

    for (int kt = 0; kt < KT; ++kt) {
        const int b = kt & 1;
        const unsigned short* Ab = As[b];
        const unsigned short* Bb = Bs[b];

        // ---- P1: ds A(m0)+B(n0) [12 reads]; stage (t+1).Bh0 -> buf^1 ----
#pragma unroll
        for (int s = 0; s < 2; ++s) {
            const int cs = ((s * 4 + quad) ^ (lm & 7)) * 8;
#pragma unroll
            for (int mt = 0; mt < 4; ++mt)
                aA[s][mt] = *(const short8*)&Ab[(wm * 128 + mt * 16 + lm) * 64 + cs];
#pragma unroll
            for (int nt = 0; nt < 2; ++nt)
                bB[s][nt] = *(const short8*)&Bb[(wn * 64 + nt * 16 + lm) * 64 + cs];
        }
        if (kt + 1 < KT) STAGE_B(b ^ 1, 0, (kt + 1) * 64);
        BAR();
        asm volatile("s_waitcnt lgkmcnt(0)" ::: "memory");
        __builtin_amdgcn_sched_barrier(0);
        __builtin_amdgcn_s_setprio(1);
#pragma unroll
        for (int s = 0; s < 2; ++s)
#pragma unroll
            for (int mt = 0; mt < 4; ++mt)
#pragma unroll
                for (int nt = 0; nt < 2; ++nt)
                    acc[mt][nt] = __builtin_amdgcn_mfma_f32_16x16x32_bf16(
                        aA[s][mt], bB[s][nt], acc[mt][nt], 0, 0, 0);
        __builtin_amdgcn_s_setprio(0);
        BAR();

        // ---- P2: ds A(m1) [8 reads]; stage (t+1).Bh1 -> buf^1 ----
#pragma unroll
        for (int s = 0; s < 2; ++s) {
            const int cs = ((s * 4 + quad) ^ (lm & 7)) * 8;
#pragma unroll
            for (int mt = 0; mt < 4; ++mt)
                aM[s][mt] = *(const short8*)&Ab[(wm * 128 + 64 + mt * 16 + lm) * 64 + cs];
        }
        if (kt + 1 < KT) STAGE_B(b ^ 1, 1, (kt + 1) * 64);
        BAR();
        asm volatile("s_waitcnt lgkmcnt(0)" ::: "memory");
        __builtin_amdgcn_sched_barrier(0);
        __builtin_amdgcn_s_setprio(1);
#pragma unroll
        for (int s = 0; s < 2; ++s)
#pragma unroll
            for (int mt = 0; mt < 4; ++mt)
#pragma unroll
                for (int nt = 0; nt < 2; ++nt)
                    acc[4 + mt][nt] = __builtin_amdgcn_mfma_f32_16x16x32_bf16(
                        aM[s][mt], bB[s][nt], acc[4 + mt][nt], 0, 0, 0);
        __builtin_amdgcn_s_setprio(0);
        BAR();

        // ---- P3: ds B(n1) [4 reads]; stage (t+2).Ah0 -> buf ----
#pragma unroll
        for (int s = 0; s < 2; ++s) {
            const int cs = ((s * 4 + quad) ^ (lm & 7)) * 8;
#pragma unroll
            for (int nt = 0; nt < 2; ++nt)
                bB[s][nt] = *(const short8*)&Bb[(wn * 64 + 32 + nt * 16 + lm) * 64 + cs];
        }
        if (kt + 2 < KT) STAGE_A(b, 0, (kt + 2) * 64);
        BAR();
        asm volatile("s_waitcnt lgkmcnt(0)" ::: "memory");
        __builtin_amdgcn_sched_barrier(0);
        __builtin_amdgcn_s_setprio(1);
#pragma unroll
        for (int s = 0; s < 2; ++s)
#pragma unroll
            for (int mt = 0; mt < 4; ++mt)
#pragma unroll
                for (int nt = 0; nt < 2; ++nt)
                    acc[4 + mt][2 + nt] = __builtin_amdgcn_mfma_f32_16x16x32_bf16(
                        aM[s][mt], bB[s][nt], acc[4 + mt][2 + nt], 0, 0, 0);
        __builtin_amdgcn_s_setprio(0);
        BAR();

        // ---- P4: no ds reads; stage (t+2).Ah1 -> buf; end-of-tile vmcnt ----
        if (kt + 2 < KT) STAGE_A(b, 1, (kt + 2) * 64);
        BAR();
        __builtin_amdgcn_s_setprio(1);
#pragma unroll
        for (int s = 0; s < 2; ++s)
#pragma unroll
            for (int mt = 0; mt < 4; ++mt)
#pragma unroll
                for (int nt = 0; nt < 2; ++nt)
                    acc[mt][2 + nt] = __builtin_amdgcn_mfma_f32_16x16x32_bf16(
                        aA[s][mt], bB[s][nt], acc[mt][2 + nt], 0, 0, 0);
        __builtin_amdgcn_s_setprio(0);
        if (kt < KT - 2) {
            asm volatile("s_waitcnt vmcnt(4)" ::: "memory");
        } else if (kt == KT - 2) {
            asm volatile("s_waitcnt vmcnt(0)" ::: "memory");
        }
        BAR();
    }
#undef STAGE_A
#undef STAGE_B

    // epilogue: D row = quad*4 + reg, col = lane&15 (m89/m91 mapping)
    if constexpr (EPI == 0) {
        unsigned short* C = (unsigned short*)Cv;
#pragma unroll
        for (int f = 0; f < 8; ++f)
#pragma unroll
            for (int g = 0; g < 4; ++g)
#pragma unroll
                for (int r = 0; r < 4; ++r) {
                    const int row = m0 + wm * 128 + f * 16 + quad * 4 + r;
                    const int col = n0 + wn * 64 + g * 16 + lm;
                    C[(size_t)row * ldc + col] = f32_to_bf16(acc[f][g][r]);
                }
    } else if constexpr (EPI == 1) {
        unsigned short* C = (unsigned short*)Cv;
        float psum[8][4];
#pragma unroll
        for (int f = 0; f < 8; ++f)
#pragma unroll
            for (int r = 0; r < 4; ++r) psum[f][r] = 0.0f;
#pragma unroll
        for (int f = 0; f < 8; ++f)
#pragma unroll
            for (int g = 0; g < 4; ++g)
#pragma unroll
                for (int r = 0; r < 4; ++r) {
                    const int row = m0 + wm * 128 + f * 16 + quad * 4 + r;
                    const int col = n0 + wn * 64 + g * 16 + lm;
                    const float p = __expf(acc[f][g][r] * scale);
                    psum[f][r] += p;
                    C[(size_t)row * ldc + col] = f32_to_bf16(p);
                }
#pragma unroll
        for (int off = 1; off <= 8; off <<= 1)
#pragma unroll
            for (int f = 0; f < 8; ++f)
#pragma unroll
                for (int r = 0; r < 4; ++r)
                    psum[f][r] += __shfl_xor(psum[f][r], off);
        if (lm == 0) {
#pragma unroll
            for (int f = 0; f < 8; ++f)
#pragma unroll
                for (int r = 0; r < 4; ++r)
                    atomicAdd(&rowsum[m0 + wm * 128 + f * 16 + quad * 4 + r],
                              psum[f][r]);
        }
    }
}

// ---- merged projections: z=0 q, z=1 k, z=2 vT (x/y grid roles swapped) ---
__global__ __launch_bounds__(512, 2) void proj256_kernel(
    const unsigned short* __restrict__ Xq, const unsigned short* __restrict__ Wq,
    unsigned short* __restrict__ qb,
    const unsigned short* __restrict__ Xk, const unsigned short* __restrict__ Wk,
    unsigned short* __restrict__ kb,
    const unsigned short* __restrict__ Wv, const unsigned short* __restrict__ Xv,
    unsigned short* __restrict__ vT) {
    const int z = blockIdx.z;
    const unsigned short* A = z == 0 ? Xq : z == 1 ? Xk : Wv;
    const unsigned short* B = z == 0 ? Wq : z == 1 ? Wk : Xv;
    unsigned short* C = z == 0 ? qb : z == 1 ? kb : vT;
    int m0, n0, ldc;
    if (z < 2) { m0 = blockIdx.x * 256; n0 = blockIdx.y * 256; ldc = 1024; }
    else       { m0 = blockIdx.y * 256; n0 = blockIdx.x * 256; ldc = 8192; }
    gemm256_body<0>(A, B, C, 1024, 1024, ldc, 1024, 1.0f, nullptr, m0, n0);
}

__global__ __launch_bounds__(512, 2) void scores256_kernel(
    const unsigned short* __restrict__ qb, const unsigned short* __restrict__ kb,
    unsigned short* __restrict__ Sc, float* __restrict__ rowsum) {
    const long z = blockIdx.z;
    gemm256_body<1>(qb + z * 2048 * 1024, kb + z * 2048 * 1024,
                    Sc + z * 2048 * 2048, 1024, 1024, 2048, 1024,
                    1.0f / 32.0f, rowsum + z * 2048,
                    blockIdx.x * 256, blockIdx.y * 256);
}

// ---------------------------------------------------------------------------
extern "C" void kernel_launch(void* const* d_in, const int* in_sizes, int n_in,
                              void* d_out, int out_size, void* d_ws, size_t ws_size,
                              hipStream_t stream) {
    const float* q_in = (const float*)d_in[0];
    const float* k_in = (const float*)d_in[1];
    const float* v_in = (const float*)d_in[2];
    const float* Qw_f = (const float*)d_in[3];
    const float* Kw_f = (const float*)d_in[4];
    const float* Vw_f = (const float*)d_in[5];
    float* out = (float*)d_out;

    const int Bb = 4, S = 2048, E = 1024;
    const size_t TOK = (size_t)Bb * S;       // 8192
    const size_t NTE = TOK * E;              // 8,388,608
    const size_t NW  = (size_t)E * E;        // 1,048,576

    unsigned short* ws = (unsigned short*)d_ws;
    unsigned short* Xq = ws;            // [8192,1024]
    unsigned short* Xk = Xq + NTE;
    unsigned short* Xv = Xk + NTE;
    unsigned short* Wq = Xv + NTE;      // [1024,1024]
    unsigned short* Wk = Wq + NW;
    unsigned short* Wv = Wk + NW;
    unsigned short* qb = Wv + NW;       // [8192,1024]
    unsigned short* kb = qb + NTE;
    unsigned short* vT = kb + NTE;      // [1024 e][8192 tok]
    unsigned short* Sc = vT + NTE;      // [4][2048][2048] exp-scores
    float* rowsum = (float*)(Sc + (size_t)Bb * S * S);  // [4][2048]

    // 1) all converts + rowsum zero, one dispatch
    {
        const long G = 3 * (long)(NTE / 4) + 3 * (long)(NW / 4) + (Bb * S / 4);
        cvt_all<<<(unsigned)(G / 256), 256, 0, stream>>>(
            q_in, k_in, v_in, Qw_f, Kw_f, Vw_f,
            Xq, Xk, Xv, Wq, Wk, Wv, rowsum);
    }

    // 2) all three projections, one dispatch (384 blocks, 256^2 8-phase)
    proj256_kernel<<<dim3(TOK / 256, E / 256, 3), 512, 0, stream>>>(
        Xq, Wq, qb, Xk, Wk, kb, Wv, Xv, vT);

    // 3) P = exp(q k^T / 32) + fp32 rowsums (256 blocks, perfect packing)
    scores256_kernel<<<dim3(S / 256, S / 256, 4), 512, 0, stream>>>(
        qb, kb, Sc, rowsum);

    // 4) out = (P @ v) / rowsum  (128^2 body, 512 blocks, 4/CU)
    pv_kernel<<<dim3(S / BM, E / BN, 4), 256, 0, stream>>>(
        Sc, vT, out, rowsum);
}

// Round 2
// 297.654 us; speedup vs baseline: 1.0168x; 1.0168x over previous
//
#include <hip/hip_runtime.h>
#include <stdint.h>

// ---------------------------------------------------------------------------
// SelfAttention: B=4, S=2048, E=1024 (single head)
//   q = Xq @ Wq^T ; k = Xk @ Wk^T ; vT = Wv @ Xv^T     (merged: 1 dispatch)
//   P = exp(q k^T / 32)  (fp32-safe; rowsums via epilogue atomics)
//   out = (P @ v) / rowsum
// R10: fix the 256^2 8-phase schedule.
//  - NO explicit lgkmcnt asm: compiler emits counted lgkm waits, so reads
//    issued for a later phase overlap this phase's MFMA (the R9 asm
//    lgkmcnt(0) forced a full drain every phase -> 24% MfmaUtil).
//  - aM (Q2's A-half) read early in S1 -> P1 MFMA runs with 8 reads in
//    flight (compiler waits lgkmcnt(8)).
//  - ALL of tile t+2 staged at S3 (A) / S4 (B) into the current buffer:
//    full-tile prefetch distance (5-6 phases > HBM latency), end-of-tile
//    s_waitcnt vmcnt(8) keeps t+2's 8 loads in flight, drains t+1's.
//    Safety: A-reads complete by P2-close, B-reads by P3-close (compiler
//    waits + closing barriers), stages issue strictly after those barriers.
// ---------------------------------------------------------------------------

typedef __attribute__((ext_vector_type(8))) short short8;       // 8 x bf16 frag
typedef __attribute__((ext_vector_type(4))) float floatx4;      // MFMA acc
typedef __attribute__((ext_vector_type(4))) unsigned short u16x4;
typedef __attribute__((ext_vector_type(4))) float f32x4v;

__device__ __forceinline__ unsigned short f32_to_bf16(float f) {
    union { float f; unsigned u; } c; c.f = f;
    unsigned u = c.u;
    return (unsigned short)((u + 0x7fffu + ((u >> 16) & 1u)) >> 16);  // RNE
}

#define G2L(g, l) __builtin_amdgcn_global_load_lds( \
    (__attribute__((address_space(1))) void*)(void*)(g), \
    (__attribute__((address_space(3))) void*)(l), 16, 0, 0)

#define BAR() __builtin_amdgcn_s_barrier()

// ---- merged fp32->bf16 converts (3x input, 3x weight) + rowsum zero ------
__global__ __launch_bounds__(256) void cvt_all(
    const float* __restrict__ q, const float* __restrict__ k,
    const float* __restrict__ v, const float* __restrict__ wq,
    const float* __restrict__ wk, const float* __restrict__ wv,
    unsigned short* __restrict__ Xq, unsigned short* __restrict__ Xk,
    unsigned short* __restrict__ Xv, unsigned short* __restrict__ Wq,
    unsigned short* __restrict__ Wk, unsigned short* __restrict__ Wv,
    float* __restrict__ rowsum) {
    const long NTE4 = 2097152;  // 8192*1024/4
    const long NW4  = 262144;   // 1024*1024/4
    long i = (long)blockIdx.x * 256 + threadIdx.x;
    const float* src;
    unsigned short* dst;
    long j;
    if (i < 3 * NTE4) {
        int a = (int)(i / NTE4); j = i - (long)a * NTE4;
        src = a == 0 ? q : a == 1 ? k : v;
        dst = a == 0 ? Xq : a == 1 ? Xk : Xv;
    } else {
        i -= 3 * NTE4;
        if (i < 3 * NW4) {
            int a = (int)(i / NW4); j = i - (long)a * NW4;
            src = a == 0 ? wq : a == 1 ? wk : wv;
            dst = a == 0 ? Wq : a == 1 ? Wk : Wv;
        } else {
            i -= 3 * NW4;           // 2048 groups -> rowsum[0..8191] = 0
            ((f32x4v*)rowsum)[i] = (f32x4v)0.0f;
            return;
        }
    }
    f32x4v f = ((const f32x4v*)src)[j];
    u16x4 o;
#pragma unroll
    for (int t = 0; t < 4; ++t) o[t] = f32_to_bf16(f[t]);
    ((u16x4*)dst)[j] = o;
}

// ===========================================================================
// 128x128 body (kept for pv: 512 blocks, 4 blocks/CU co-resident)
// ===========================================================================
#define BM 128
#define BN 128
#define BK 64

template <int EPI>
__device__ __forceinline__ void gemm_body(
    const unsigned short* __restrict__ A, const unsigned short* __restrict__ B,
    void* __restrict__ Cv, int lda, int ldb, int ldc, int K, float scale,
    float* __restrict__ rowsum, int m0, int n0) {
    __shared__ unsigned short As[BM * BK];
    __shared__ unsigned short Bs[BN * BK];

    const int tid  = threadIdx.x;
    const int wave = tid >> 6;
    const int lane = tid & 63;
    const int lm   = lane & 15;
    const int quad = lane >> 4;
    const int wm   = wave >> 1;
    const int wn   = wave & 1;

    const int srow8 = lane >> 3;
    const int gcol  = ((lane & 7) ^ srow8) * 8;

    floatx4 acc[4][4];
#pragma unroll
    for (int i = 0; i < 4; ++i)
#pragma unroll
        for (int j = 0; j < 4; ++j) acc[i][j] = (floatx4)0.0f;

    for (int k0 = 0; k0 < K; k0 += BK) {
#pragma unroll
        for (int i = 0; i < 4; ++i) {
            const int rbase = wave * 32 + i * 8;
            G2L(A + (size_t)(m0 + rbase + srow8) * lda + k0 + gcol,
                &As[rbase * BK]);
            G2L(B + (size_t)(n0 + rbase + srow8) * ldb + k0 + gcol,
                &Bs[rbase * BK]);
        }
        __syncthreads();

#pragma unroll
        for (int s = 0; s < 2; ++s) {
            short8 af[4], bf[4];
#pragma unroll
            for (int t = 0; t < 4; ++t) {
                const int cs = ((s * 4 + quad) ^ (lm & 7)) * 8;
                af[t] = *(const short8*)&As[(wm * 64 + t * 16 + lm) * BK + cs];
                bf[t] = *(const short8*)&Bs[(wn * 64 + t * 16 + lm) * BK + cs];
            }
#pragma unroll
            for (int mt = 0; mt < 4; ++mt)
#pragma unroll
                for (int nt = 0; nt < 4; ++nt)
                    acc[mt][nt] = __builtin_amdgcn_mfma_f32_16x16x32_bf16(
                        af[mt], bf[nt], acc[mt][nt], 0, 0, 0);
        }
        __syncthreads();
    }

    if constexpr (EPI == 2) {
        float* C = (float*)Cv;
#pragma unroll
        for (int mt = 0; mt < 4; ++mt)
#pragma unroll
            for (int r = 0; r < 4; ++r) {
                const int row = m0 + wm * 64 + mt * 16 + quad * 4 + r;
                const float inv = 1.0f / rowsum[row];
#pragma unroll
                for (int nt = 0; nt < 4; ++nt) {
                    const int col = n0 + wn * 64 + nt * 16 + lm;
                    C[(size_t)row * ldc + col] = acc[mt][nt][r] * inv;
                }
            }
    }
}

__global__ __launch_bounds__(256, 4) void pv_kernel(
    const unsigned short* __restrict__ Sc, const unsigned short* __restrict__ vT,
    float* __restrict__ out, float* __restrict__ rowsum) {
    const long z = blockIdx.z;
    gemm_body<2>(Sc + z * 2048 * 2048, vT + z * 2048,
                 out + z * 2048 * 1024, 2048, 8192, 1024, 2048,
                 1.0f, rowsum + z * 2048,
                 blockIdx.x * BM, blockIdx.y * BN);
}

// ===========================================================================
// 256x256 8-phase body, v2 schedule.
//   512 thr = 8 waves (2M x 4N), per-wave C = 128x64, BK=64, LDS 128 KiB.
//   Quadrants: Q1=(m0,n0) Q2=(m1,n0) Q3=(m1,n1) Q4=(m0,n1).
//   S1: read aA(12 incl bN0) then aM(8)   -> P1 MFMA Q1 (lgkm counted: aM in flight)
//   S2: (nothing)                          -> P2 MFMA Q2
//   S3: read bN1(4); stage A(t+2) 4xG2L   -> P3 MFMA Q3
//   S4: stage B(t+2) 4xG2L                -> P4 MFMA Q4; vmcnt(8); BAR
//   No lgkm asm anywhere: compiler emits counted waits (m97 behavior).
// ===========================================================================
template <int EPI>
__device__ __forceinline__ void gemm256_body(
    const unsigned short* __restrict__ A, const unsigned short* __restrict__ B,
    void* __restrict__ Cv, int lda, int ldb, int ldc, int K, float scale,
    float* __restrict__ rowsum, int m0, int n0) {
    __shared__ unsigned short As[2][256 * 64];
    __shared__ unsigned short Bs[2][256 * 64];

    const int tid   = threadIdx.x;
    const int wave  = tid >> 6;      // 0..7
    const int lane  = tid & 63;
    const int lm    = lane & 15;     // MFMA row-in-frag
    const int quad  = lane >> 4;     // 0..3
    const int wm    = wave >> 2;     // 0..1  (wave tile 2x4)
    const int wn    = wave & 3;      // 0..3
    const int srow8 = lane >> 3;
    const int gcol  = ((lane & 7) ^ srow8) * 8;  // pre-swizzled global col
    const int KT    = K >> 6;

#define STAGE_A(buf, half, kcol) do { \
        const int r0_ = (half) * 128 + wave * 8; \
        G2L(A + (size_t)(m0 + r0_ + srow8) * lda + (kcol) + gcol, \
            &As[buf][r0_ * 64]); \
        G2L(A + (size_t)(m0 + r0_ + 64 + srow8) * lda + (kcol) + gcol, \
            &As[buf][(r0_ + 64) * 64]); \
    } while (0)
#define STAGE_B(buf, half, kcol) do { \
        const int r0_ = (half) * 128 + wave * 8; \
        G2L(B + (size_t)(n0 + r0_ + srow8) * ldb + (kcol) + gcol, \
            &Bs[buf][r0_ * 64]); \
        G2L(B + (size_t)(n0 + r0_ + 64 + srow8) * ldb + (kcol) + gcol, \
            &Bs[buf][(r0_ + 64) * 64]); \
    } while (0)

    floatx4 acc[8][4];
#pragma unroll
    for (int i = 0; i < 8; ++i)
#pragma unroll
        for (int j = 0; j < 4; ++j) acc[i][j] = (floatx4)0.0f;

    // prologue: tile0 -> buf0, tile1 -> buf1 (8 loads each); vmcnt(8) => t0 landed
    STAGE_A(0, 0, 0); STAGE_A(0, 1, 0); STAGE_B(0, 0, 0); STAGE_B(0, 1, 0);
    if (KT > 1) {
        STAGE_A(1, 0, 64); STAGE_A(1, 1, 64);
        STAGE_B(1, 0, 64); STAGE_B(1, 1, 64);
        asm volatile("s_waitcnt vmcnt(8)" ::: "memory");
    } else {
        asm volatile("s_waitcnt vmcnt(0)" ::: "memory");
    }
    BAR();

    short8 aA[2][4];   // A half m0  (Q1, Q4)
    short8 aM[2][4];   // A half m1  (Q2, Q3)
    short8 bB[2][2];   // B half: n0 during Q1/Q2, overwritten with n1 at S3

    for (int kt = 0; kt < KT; ++kt) {
        const int b = kt & 1;
        const unsigned short* Ab = As[b];
        const unsigned short* Bb = Bs[b];

        // ---- S1: reads for Q1 (aA + bB=n0), then read-ahead aM (Q2) ----
#pragma unroll
        for (int s = 0; s < 2; ++s) {
            const int cs = ((s * 4 + quad) ^ (lm & 7)) * 8;
#pragma unroll
            for (int mt = 0; mt < 4; ++mt)
                aA[s][mt] = *(const short8*)&Ab[(wm * 128 + mt * 16 + lm) * 64 + cs];
#pragma unroll
            for (int nt = 0; nt < 2; ++nt)
                bB[s][nt] = *(const short8*)&Bb[(wn * 64 + nt * 16 + lm) * 64 + cs];
        }
#pragma unroll
        for (int s = 0; s < 2; ++s) {
            const int cs = ((s * 4 + quad) ^ (lm & 7)) * 8;
#pragma unroll
            for (int mt = 0; mt < 4; ++mt)
                aM[s][mt] = *(const short8*)&Ab[(wm * 128 + 64 + mt * 16 + lm) * 64 + cs];
        }
        BAR();
        // P1: MFMA Q1 (compiler waits counted lgkm; aM stays in flight)
        __builtin_amdgcn_s_setprio(1);
#pragma unroll
        for (int s = 0; s < 2; ++s)
#pragma unroll
            for (int mt = 0; mt < 4; ++mt)
#pragma unroll
                for (int nt = 0; nt < 2; ++nt)
                    acc[mt][nt] = __builtin_amdgcn_mfma_f32_16x16x32_bf16(
                        aA[s][mt], bB[s][nt], acc[mt][nt], 0, 0, 0);
        __builtin_amdgcn_s_setprio(0);
        BAR();

        // ---- S2: (no reads, no stages) ----
        BAR();
        // P2: MFMA Q2
        __builtin_amdgcn_s_setprio(1);
#pragma unroll
        for (int s = 0; s < 2; ++s)
#pragma unroll
            for (int mt = 0; mt < 4; ++mt)
#pragma unroll
                for (int nt = 0; nt < 2; ++nt)
                    acc[4 + mt][nt] = __builtin_amdgcn_mfma_f32_16x16x32_bf16(
                        aM[s][mt], bB[s][nt], acc[4 + mt][nt], 0, 0, 0);
        __builtin_amdgcn_s_setprio(0);
        BAR();

        // ---- S3: read bB=n1 (A-reads all done by P2-close); stage A(t+2) ----
#pragma unroll
        for (int s = 0; s < 2; ++s) {
            const int cs = ((s * 4 + quad) ^ (lm & 7)) * 8;
#pragma unroll
            for (int nt = 0; nt < 2; ++nt)
                bB[s][nt] = *(const short8*)&Bb[(wn * 64 + 32 + nt * 16 + lm) * 64 + cs];
        }
        if (kt + 2 < KT) { STAGE_A(b, 0, (kt + 2) * 64); STAGE_A(b, 1, (kt + 2) * 64); }
        BAR();
        // P3: MFMA Q3
        __builtin_amdgcn_s_setprio(1);
#pragma unroll
        for (int s = 0; s < 2; ++s)
#pragma unroll
            for (int mt = 0; mt < 4; ++mt)
#pragma unroll
                for (int nt = 0; nt < 2; ++nt)
                    acc[4 + mt][2 + nt] = __builtin_amdgcn_mfma_f32_16x16x32_bf16(
                        aM[s][mt], bB[s][nt], acc[4 + mt][2 + nt], 0, 0, 0);
        __builtin_amdgcn_s_setprio(0);
        BAR();

        // ---- S4: stage B(t+2) (B-reads all done by P3-close) ----
        if (kt + 2 < KT) { STAGE_B(b, 0, (kt + 2) * 64); STAGE_B(b, 1, (kt + 2) * 64); }
        BAR();
        // P4: MFMA Q4; then counted vmcnt => tile t+1 landed; publish barrier
        __builtin_amdgcn_s_setprio(1);
#pragma unroll
        for (int s = 0; s < 2; ++s)
#pragma unroll
            for (int mt = 0; mt < 4; ++mt)
#pragma unroll
                for (int nt = 0; nt < 2; ++nt)
                    acc[mt][2 + nt] = __builtin_amdgcn_mfma_f32_16x16x32_bf16(
                        aA[s][mt], bB[s][nt], acc[mt][2 + nt], 0, 0, 0);
        __builtin_amdgcn_s_setprio(0);
        if (kt + 2 < KT) {
            asm volatile("s_waitcnt vmcnt(8)" ::: "memory");
        } else if (kt + 1 < KT) {
            asm volatile("s_waitcnt vmcnt(0)" ::: "memory");
        }
        BAR();
    }
#undef STAGE_A
#undef STAGE_B

    // epilogue: D row = quad*4 + reg, col = lane&15 (m89/m91 mapping)
    if constexpr (EPI == 0) {
        unsigned short* C = (unsigned short*)Cv;
#pragma unroll
        for (int f = 0; f < 8; ++f)
#pragma unroll
            for (int g = 0; g < 4; ++g)
#pragma unroll
                for (int r = 0; r < 4; ++r) {
                    const int row = m0 + wm * 128 + f * 16 + quad * 4 + r;
                    const int col = n0 + wn * 64 + g * 16 + lm;
                    C[(size_t)row * ldc + col] = f32_to_bf16(acc[f][g][r]);
                }
    } else if constexpr (EPI == 1) {
        unsigned short* C = (unsigned short*)Cv;
        float psum[8][4];
#pragma unroll
        for (int f = 0; f < 8; ++f)
#pragma unroll
            for (int r = 0; r < 4; ++r) psum[f][r] = 0.0f;
#pragma unroll
        for (int f = 0; f < 8; ++f)
#pragma unroll
            for (int g = 0; g < 4; ++g)
#pragma unroll
                for (int r = 0; r < 4; ++r) {
                    const int row = m0 + wm * 128 + f * 16 + quad * 4 + r;
                    const int col = n0 + wn * 64 + g * 16 + lm;
                    const float p = __expf(acc[f][g][r] * scale);
                    psum[f][r] += p;
                    C[(size_t)row * ldc + col] = f32_to_bf16(p);
                }
#pragma unroll
        for (int off = 1; off <= 8; off <<= 1)
#pragma unroll
            for (int f = 0; f < 8; ++f)
#pragma unroll
                for (int r = 0; r < 4; ++r)
                    psum[f][r] += __shfl_xor(psum[f][r], off);
        if (lm == 0) {
#pragma unroll
            for (int f = 0; f < 8; ++f)
#pragma unroll
                for (int r = 0; r < 4; ++r)
                    atomicAdd(&rowsum[m0 + wm * 128 + f * 16 + quad * 4 + r],
                              psum[f][r]);
        }
    }
}

// ---- merged projections: z=0 q, z=1 k, z=2 vT (x/y grid roles swapped) ---
__global__ __launch_bounds__(512, 2) void proj256_kernel(
    const unsigned short* __restrict__ Xq, const unsigned short* __restrict__ Wq,
    unsigned short* __restrict__ qb,
    const unsigned short* __restrict__ Xk, const unsigned short* __restrict__ Wk,
    unsigned short* __restrict__ kb,
    const unsigned short* __restrict__ Wv, const unsigned short* __restrict__ Xv,
    unsigned short* __restrict__ vT) {
    const int z = blockIdx.z;
    const unsigned short* A = z == 0 ? Xq : z == 1 ? Xk : Wv;
    const unsigned short* B = z == 0 ? Wq : z == 1 ? Wk : Xv;
    unsigned short* C = z == 0 ? qb : z == 1 ? kb : vT;
    int m0, n0, ldc;
    if (z < 2) { m0 = blockIdx.x * 256; n0 = blockIdx.y * 256; ldc = 1024; }
    else       { m0 = blockIdx.y * 256; n0 = blockIdx.x * 256; ldc = 8192; }
    gemm256_body<0>(A, B, C, 1024, 1024, ldc, 1024, 1.0f, nullptr, m0, n0);
}

__global__ __launch_bounds__(512, 2) void scores256_kernel(
    const unsigned short* __restrict__ qb, const unsigned short* __restrict__ kb,
    unsigned short* __restrict__ Sc, float* __restrict__ rowsum) {
    const long z = blockIdx.z;
    gemm256_body<1>(qb + z * 2048 * 1024, kb + z * 2048 * 1024,
                    Sc + z * 2048 * 2048, 1024, 1024, 2048, 1024,
                    1.0f / 32.0f, rowsum + z * 2048,
                    blockIdx.x * 256, blockIdx.y * 256);
}

// ---------------------------------------------------------------------------
extern "C" void kernel_launch(void* const* d_in, const int* in_sizes, int n_in,
                              void* d_out, int out_size, void* d_ws, size_t ws_size,
                              hipStream_t stream) {
    const float* q_in = (const float*)d_in[0];
    const float* k_in = (const float*)d_in[1];
    const float* v_in = (const float*)d_in[2];
    const float* Qw_f = (const float*)d_in[3];
    const float* Kw_f = (const float*)d_in[4];
    const float* Vw_f = (const float*)d_in[5];
    float* out = (float*)d_out;

    const int Bb = 4, S = 2048, E = 1024;
    const size_t TOK = (size_t)Bb * S;       // 8192
    const size_t NTE = TOK * E;              // 8,388,608
    const size_t NW  = (size_t)E * E;        // 1,048,576

    unsigned short* ws = (unsigned short*)d_ws;
    unsigned short* Xq = ws;            // [8192,1024]
    unsigned short* Xk = Xq + NTE;
    unsigned short* Xv = Xk + NTE;
    unsigned short* Wq = Xv + NTE;      // [1024,1024]
    unsigned short* Wk = Wq + NW;
    unsigned short* Wv = Wk + NW;
    unsigned short* qb = Wv + NW;       // [8192,1024]
    unsigned short* kb = qb + NTE;
    unsigned short* vT = kb + NTE;      // [1024 e][8192 tok]
    unsigned short* Sc = vT + NTE;      // [4][2048][2048] exp-scores
    float* rowsum = (float*)(Sc + (size_t)Bb * S * S);  // [4][2048]

    // 1) all converts + rowsum zero, one dispatch
    {
        const long G = 3 * (long)(NTE / 4) + 3 * (long)(NW / 4) + (Bb * S / 4);
        cvt_all<<<(unsigned)(G / 256), 256, 0, stream>>>(
            q_in, k_in, v_in, Qw_f, Kw_f, Vw_f,
            Xq, Xk, Xv, Wq, Wk, Wv, rowsum);
    }

    // 2) all three projections, one dispatch (384 blocks, 256^2 8-phase)
    proj256_kernel<<<dim3(TOK / 256, E / 256, 3), 512, 0, stream>>>(
        Xq, Wq, qb, Xk, Wk, kb, Wv, Xv, vT);

    // 3) P = exp(q k^T / 32) + fp32 rowsums (256 blocks, perfect packing)
    scores256_kernel<<<dim3(S / 256, S / 256, 4), 512, 0, stream>>>(
        qb, kb, Sc, rowsum);

    // 4) out = (P @ v) / rowsum  (128^2 body, 512 blocks, 4/CU)
    pv_kernel<<<dim3(S / BM, E / BN, 4), 256, 0, stream>>>(
        Sc, vT, out, rowsum);
}

// Round 3
// 289.912 us; speedup vs baseline: 1.0440x; 1.0267x over previous
//
#include <hip/hip_runtime.h>
#include <stdint.h>

// ---------------------------------------------------------------------------
// SelfAttention: B=4, S=2048, E=1024 (single head)
//   q = Xq @ Wq^T ; k = Xk @ Wk^T ; vT = Wv @ Xv^T     (merged: 1 dispatch)
//   P = exp(q k^T / 32)  (fp32-safe; rowsums via epilogue atomics)
//   out = (P @ v) / rowsum
// R11: proj reverted to the proven 128^2 body (54.7 us, 942 TF — the
// m97-structure ceiling). Two 256^2 8-phase ports landed at 24-27% MfmaUtil
// (72-78 us): the m232 open quadrant — overlap not reproducible blind.
// scores KEEPS the 256^2 body: measured −7 us vs 128^2 scores across two
// rounds (perfect 256-block packing + halved epilogue/atomic overhead).
// ---------------------------------------------------------------------------

typedef __attribute__((ext_vector_type(8))) short short8;       // 8 x bf16 frag
typedef __attribute__((ext_vector_type(4))) float floatx4;      // MFMA acc
typedef __attribute__((ext_vector_type(4))) unsigned short u16x4;
typedef __attribute__((ext_vector_type(4))) float f32x4v;

__device__ __forceinline__ unsigned short f32_to_bf16(float f) {
    union { float f; unsigned u; } c; c.f = f;
    unsigned u = c.u;
    return (unsigned short)((u + 0x7fffu + ((u >> 16) & 1u)) >> 16);  // RNE
}

#define G2L(g, l) __builtin_amdgcn_global_load_lds( \
    (__attribute__((address_space(1))) void*)(void*)(g), \
    (__attribute__((address_space(3))) void*)(l), 16, 0, 0)

#define BAR() __builtin_amdgcn_s_barrier()

// ---- merged fp32->bf16 converts (3x input, 3x weight) + rowsum zero ------
__global__ __launch_bounds__(256) void cvt_all(
    const float* __restrict__ q, const float* __restrict__ k,
    const float* __restrict__ v, const float* __restrict__ wq,
    const float* __restrict__ wk, const float* __restrict__ wv,
    unsigned short* __restrict__ Xq, unsigned short* __restrict__ Xk,
    unsigned short* __restrict__ Xv, unsigned short* __restrict__ Wq,
    unsigned short* __restrict__ Wk, unsigned short* __restrict__ Wv,
    float* __restrict__ rowsum) {
    const long NTE4 = 2097152;  // 8192*1024/4
    const long NW4  = 262144;   // 1024*1024/4
    long i = (long)blockIdx.x * 256 + threadIdx.x;
    const float* src;
    unsigned short* dst;
    long j;
    if (i < 3 * NTE4) {
        int a = (int)(i / NTE4); j = i - (long)a * NTE4;
        src = a == 0 ? q : a == 1 ? k : v;
        dst = a == 0 ? Xq : a == 1 ? Xk : Xv;
    } else {
        i -= 3 * NTE4;
        if (i < 3 * NW4) {
            int a = (int)(i / NW4); j = i - (long)a * NW4;
            src = a == 0 ? wq : a == 1 ? wk : wv;
            dst = a == 0 ? Wq : a == 1 ? Wk : Wv;
        } else {
            i -= 3 * NW4;           // 2048 groups -> rowsum[0..8191] = 0
            ((f32x4v*)rowsum)[i] = (f32x4v)0.0f;
            return;
        }
    }
    f32x4v f = ((const f32x4v*)src)[j];
    u16x4 o;
#pragma unroll
    for (int t = 0; t < 4; ++t) o[t] = f32_to_bf16(f[t]);
    ((u16x4*)dst)[j] = o;
}

// ===========================================================================
// 128x128 body (proj + pv: 4-deep blocks/CU, proven 942 TF structure)
// ===========================================================================
#define BM 128
#define BN 128
#define BK 64

// EPI: 0 = store bf16; 2 = store fp32 x / rowsum[row]
template <int EPI>
__device__ __forceinline__ void gemm_body(
    const unsigned short* __restrict__ A, const unsigned short* __restrict__ B,
    void* __restrict__ Cv, int lda, int ldb, int ldc, int K, float scale,
    float* __restrict__ rowsum, int m0, int n0) {
    __shared__ unsigned short As[BM * BK];
    __shared__ unsigned short Bs[BN * BK];

    const int tid  = threadIdx.x;
    const int wave = tid >> 6;
    const int lane = tid & 63;
    const int lm   = lane & 15;
    const int quad = lane >> 4;
    const int wm   = wave >> 1;
    const int wn   = wave & 1;

    const int srow8 = lane >> 3;
    const int gcol  = ((lane & 7) ^ srow8) * 8;

    floatx4 acc[4][4];
#pragma unroll
    for (int i = 0; i < 4; ++i)
#pragma unroll
        for (int j = 0; j < 4; ++j) acc[i][j] = (floatx4)0.0f;

    for (int k0 = 0; k0 < K; k0 += BK) {
#pragma unroll
        for (int i = 0; i < 4; ++i) {
            const int rbase = wave * 32 + i * 8;
            G2L(A + (size_t)(m0 + rbase + srow8) * lda + k0 + gcol,
                &As[rbase * BK]);
            G2L(B + (size_t)(n0 + rbase + srow8) * ldb + k0 + gcol,
                &Bs[rbase * BK]);
        }
        __syncthreads();

#pragma unroll
        for (int s = 0; s < 2; ++s) {
            short8 af[4], bf[4];
#pragma unroll
            for (int t = 0; t < 4; ++t) {
                const int cs = ((s * 4 + quad) ^ (lm & 7)) * 8;
                af[t] = *(const short8*)&As[(wm * 64 + t * 16 + lm) * BK + cs];
                bf[t] = *(const short8*)&Bs[(wn * 64 + t * 16 + lm) * BK + cs];
            }
#pragma unroll
            for (int mt = 0; mt < 4; ++mt)
#pragma unroll
                for (int nt = 0; nt < 4; ++nt)
                    acc[mt][nt] = __builtin_amdgcn_mfma_f32_16x16x32_bf16(
                        af[mt], bf[nt], acc[mt][nt], 0, 0, 0);
        }
        __syncthreads();
    }

    // epilogue: D row = quad*4 + reg, col = lane&15 (m89/m91 mapping)
    if constexpr (EPI == 0) {
        unsigned short* C = (unsigned short*)Cv;
#pragma unroll
        for (int mt = 0; mt < 4; ++mt)
#pragma unroll
            for (int nt = 0; nt < 4; ++nt)
#pragma unroll
                for (int r = 0; r < 4; ++r) {
                    const int row = m0 + wm * 64 + mt * 16 + quad * 4 + r;
                    const int col = n0 + wn * 64 + nt * 16 + lm;
                    C[(size_t)row * ldc + col] = f32_to_bf16(acc[mt][nt][r]);
                }
    } else if constexpr (EPI == 2) {
        float* C = (float*)Cv;
#pragma unroll
        for (int mt = 0; mt < 4; ++mt)
#pragma unroll
            for (int r = 0; r < 4; ++r) {
                const int row = m0 + wm * 64 + mt * 16 + quad * 4 + r;
                const float inv = 1.0f / rowsum[row];
#pragma unroll
                for (int nt = 0; nt < 4; ++nt) {
                    const int col = n0 + wn * 64 + nt * 16 + lm;
                    C[(size_t)row * ldc + col] = acc[mt][nt][r] * inv;
                }
            }
    }
}

// ---- merged projections: z=0 q, z=1 k, z=2 vT (x/y grid roles swapped) ---
__global__ __launch_bounds__(256, 4) void proj_kernel(
    const unsigned short* __restrict__ Xq, const unsigned short* __restrict__ Wq,
    unsigned short* __restrict__ qb,
    const unsigned short* __restrict__ Xk, const unsigned short* __restrict__ Wk,
    unsigned short* __restrict__ kb,
    const unsigned short* __restrict__ Wv, const unsigned short* __restrict__ Xv,
    unsigned short* __restrict__ vT) {
    const int z = blockIdx.z;
    const unsigned short* A = z == 0 ? Xq : z == 1 ? Xk : Wv;
    const unsigned short* B = z == 0 ? Wq : z == 1 ? Wk : Xv;
    unsigned short* C = z == 0 ? qb : z == 1 ? kb : vT;
    int m0, n0, ldc;
    if (z < 2) { m0 = blockIdx.x * BM; n0 = blockIdx.y * BN; ldc = 1024; }
    else       { m0 = blockIdx.y * BM; n0 = blockIdx.x * BN; ldc = 8192; }
    gemm_body<0>(A, B, C, 1024, 1024, ldc, 1024, 1.0f, nullptr, m0, n0);
}

__global__ __launch_bounds__(256, 4) void pv_kernel(
    const unsigned short* __restrict__ Sc, const unsigned short* __restrict__ vT,
    float* __restrict__ out, float* __restrict__ rowsum) {
    const long z = blockIdx.z;
    gemm_body<2>(Sc + z * 2048 * 2048, vT + z * 2048,
                 out + z * 2048 * 1024, 2048, 8192, 1024, 2048,
                 1.0f, rowsum + z * 2048,
                 blockIdx.x * BM, blockIdx.y * BN);
}

// ===========================================================================
// 256x256 8-phase body (scores only: 256 blocks = perfect 1/CU packing,
// measured −7 us vs the 128^2 scores across two schedule variants).
// ===========================================================================
template <int EPI>
__device__ __forceinline__ void gemm256_body(
    const unsigned short* __restrict__ A, const unsigned short* __restrict__ B,
    void* __restrict__ Cv, int lda, int ldb, int ldc, int K, float scale,
    float* __restrict__ rowsum, int m0, int n0) {
    __shared__ unsigned short As[2][256 * 64];
    __shared__ unsigned short Bs[2][256 * 64];

    const int tid   = threadIdx.x;
    const int wave  = tid >> 6;      // 0..7
    const int lane  = tid & 63;
    const int lm    = lane & 15;     // MFMA row-in-frag
    const int quad  = lane >> 4;     // 0..3
    const int wm    = wave >> 2;     // 0..1  (wave tile 2x4)
    const int wn    = wave & 3;      // 0..3
    const int srow8 = lane >> 3;
    const int gcol  = ((lane & 7) ^ srow8) * 8;  // pre-swizzled global col
    const int KT    = K >> 6;

#define STAGE_A(buf, half, kcol) do { \
        const int r0_ = (half) * 128 + wave * 8; \
        G2L(A + (size_t)(m0 + r0_ + srow8) * lda + (kcol) + gcol, \
            &As[buf][r0_ * 64]); \
        G2L(A + (size_t)(m0 + r0_ + 64 + srow8) * lda + (kcol) + gcol, \
            &As[buf][(r0_ + 64) * 64]); \
    } while (0)
#define STAGE_B(buf, half, kcol) do { \
        const int r0_ = (half) * 128 + wave * 8; \
        G2L(B + (size_t)(n0 + r0_ + srow8) * ldb + (kcol) + gcol, \
            &Bs[buf][r0_ * 64]); \
        G2L(B + (size_t)(n0 + r0_ + 64 + srow8) * ldb + (kcol) + gcol, \
            &Bs[buf][(r0_ + 64) * 64]); \
    } while (0)

    floatx4 acc[8][4];
#pragma unroll
    for (int i = 0; i < 8; ++i)
#pragma unroll
        for (int j = 0; j < 4; ++j) acc[i][j] = (floatx4)0.0f;

    // prologue: tile0 -> buf0, tile1 -> buf1 (8 loads each); vmcnt(8) => t0 landed
    STAGE_A(0, 0, 0); STAGE_A(0, 1, 0); STAGE_B(0, 0, 0); STAGE_B(0, 1, 0);
    if (KT > 1) {
        STAGE_A(1, 0, 64); STAGE_A(1, 1, 64);
        STAGE_B(1, 0, 64); STAGE_B(1, 1, 64);
        asm volatile("s_waitcnt vmcnt(8)" ::: "memory");
    } else {
        asm volatile("s_waitcnt vmcnt(0)" ::: "memory");
    }
    BAR();

    short8 aA[2][4];   // A half m0  (Q1, Q4)
    short8 aM[2][4];   // A half m1  (Q2, Q3)
    short8 bB[2][2];   // B half: n0 during Q1/Q2, overwritten with n1 at S3

    for (int kt = 0; kt < KT; ++kt) {
        const int b = kt & 1;
        const unsigned short* Ab = As[b];
        const unsigned short* Bb = Bs[b];

        // ---- S1: reads for Q1 (aA + bB=n0), then read-ahead aM (Q2) ----
#pragma unroll
        for (int s = 0; s < 2; ++s) {
            const int cs = ((s * 4 + quad) ^ (lm & 7)) * 8;
#pragma unroll
            for (int mt = 0; mt < 4; ++mt)
                aA[s][mt] = *(const short8*)&Ab[(wm * 128 + mt * 16 + lm) * 64 + cs];
#pragma unroll
            for (int nt = 0; nt < 2; ++nt)
                bB[s][nt] = *(const short8*)&Bb[(wn * 64 + nt * 16 + lm) * 64 + cs];
        }
#pragma unroll
        for (int s = 0; s < 2; ++s) {
            const int cs = ((s * 4 + quad) ^ (lm & 7)) * 8;
#pragma unroll
            for (int mt = 0; mt < 4; ++mt)
                aM[s][mt] = *(const short8*)&Ab[(wm * 128 + 64 + mt * 16 + lm) * 64 + cs];
        }
        BAR();
        // P1: MFMA Q1 (compiler waits counted lgkm; aM stays in flight)
        __builtin_amdgcn_s_setprio(1);
#pragma unroll
        for (int s = 0; s < 2; ++s)
#pragma unroll
            for (int mt = 0; mt < 4; ++mt)
#pragma unroll
                for (int nt = 0; nt < 2; ++nt)
                    acc[mt][nt] = __builtin_amdgcn_mfma_f32_16x16x32_bf16(
                        aA[s][mt], bB[s][nt], acc[mt][nt], 0, 0, 0);
        __builtin_amdgcn_s_setprio(0);
        BAR();

        // ---- S2: (no reads, no stages) ----
        BAR();
        // P2: MFMA Q2
        __builtin_amdgcn_s_setprio(1);
#pragma unroll
        for (int s = 0; s < 2; ++s)
#pragma unroll
            for (int mt = 0; mt < 4; ++mt)
#pragma unroll
                for (int nt = 0; nt < 2; ++nt)
                    acc[4 + mt][nt] = __builtin_amdgcn_mfma_f32_16x16x32_bf16(
                        aM[s][mt], bB[s][nt], acc[4 + mt][nt], 0, 0, 0);
        __builtin_amdgcn_s_setprio(0);
        BAR();

        // ---- S3: read bB=n1 (A-reads all done by P2-close); stage A(t+2) ----
#pragma unroll
        for (int s = 0; s < 2; ++s) {
            const int cs = ((s * 4 + quad) ^ (lm & 7)) * 8;
#pragma unroll
            for (int nt = 0; nt < 2; ++nt)
                bB[s][nt] = *(const short8*)&Bb[(wn * 64 + 32 + nt * 16 + lm) * 64 + cs];
        }
        if (kt + 2 < KT) { STAGE_A(b, 0, (kt + 2) * 64); STAGE_A(b, 1, (kt + 2) * 64); }
        BAR();
        // P3: MFMA Q3
        __builtin_amdgcn_s_setprio(1);
#pragma unroll
        for (int s = 0; s < 2; ++s)
#pragma unroll
            for (int mt = 0; mt < 4; ++mt)
#pragma unroll
                for (int nt = 0; nt < 2; ++nt)
                    acc[4 + mt][2 + nt] = __builtin_amdgcn_mfma_f32_16x16x32_bf16(
                        aM[s][mt], bB[s][nt], acc[4 + mt][2 + nt], 0, 0, 0);
        __builtin_amdgcn_s_setprio(0);
        BAR();

        // ---- S4: stage B(t+2) (B-reads all done by P3-close) ----
        if (kt + 2 < KT) { STAGE_B(b, 0, (kt + 2) * 64); STAGE_B(b, 1, (kt + 2) * 64); }
        BAR();
        // P4: MFMA Q4; then counted vmcnt => tile t+1 landed; publish barrier
        __builtin_amdgcn_s_setprio(1);
#pragma unroll
        for (int s = 0; s < 2; ++s)
#pragma unroll
            for (int mt = 0; mt < 4; ++mt)
#pragma unroll
                for (int nt = 0; nt < 2; ++nt)
                    acc[mt][2 + nt] = __builtin_amdgcn_mfma_f32_16x16x32_bf16(
                        aA[s][mt], bB[s][nt], acc[mt][2 + nt], 0, 0, 0);
        __builtin_amdgcn_s_setprio(0);
        if (kt + 2 < KT) {
            asm volatile("s_waitcnt vmcnt(8)" ::: "memory");
        } else if (kt + 1 < KT) {
            asm volatile("s_waitcnt vmcnt(0)" ::: "memory");
        }
        BAR();
    }
#undef STAGE_A
#undef STAGE_B

    // epilogue: D row = quad*4 + reg, col = lane&15 (m89/m91 mapping)
    if constexpr (EPI == 1) {
        unsigned short* C = (unsigned short*)Cv;
        float psum[8][4];
#pragma unroll
        for (int f = 0; f < 8; ++f)
#pragma unroll
            for (int r = 0; r < 4; ++r) psum[f][r] = 0.0f;
#pragma unroll
        for (int f = 0; f < 8; ++f)
#pragma unroll
            for (int g = 0; g < 4; ++g)
#pragma unroll
                for (int r = 0; r < 4; ++r) {
                    const int row = m0 + wm * 128 + f * 16 + quad * 4 + r;
                    const int col = n0 + wn * 64 + g * 16 + lm;
                    const float p = __expf(acc[f][g][r] * scale);
                    psum[f][r] += p;
                    C[(size_t)row * ldc + col] = f32_to_bf16(p);
                }
#pragma unroll
        for (int off = 1; off <= 8; off <<= 1)
#pragma unroll
            for (int f = 0; f < 8; ++f)
#pragma unroll
                for (int r = 0; r < 4; ++r)
                    psum[f][r] += __shfl_xor(psum[f][r], off);
        if (lm == 0) {
#pragma unroll
            for (int f = 0; f < 8; ++f)
#pragma unroll
                for (int r = 0; r < 4; ++r)
                    atomicAdd(&rowsum[m0 + wm * 128 + f * 16 + quad * 4 + r],
                              psum[f][r]);
        }
    }
}

__global__ __launch_bounds__(512, 2) void scores256_kernel(
    const unsigned short* __restrict__ qb, const unsigned short* __restrict__ kb,
    unsigned short* __restrict__ Sc, float* __restrict__ rowsum) {
    const long z = blockIdx.z;
    gemm256_body<1>(qb + z * 2048 * 1024, kb + z * 2048 * 1024,
                    Sc + z * 2048 * 2048, 1024, 1024, 2048, 1024,
                    1.0f / 32.0f, rowsum + z * 2048,
                    blockIdx.x * 256, blockIdx.y * 256);
}

// ---------------------------------------------------------------------------
extern "C" void kernel_launch(void* const* d_in, const int* in_sizes, int n_in,
                              void* d_out, int out_size, void* d_ws, size_t ws_size,
                              hipStream_t stream) {
    const float* q_in = (const float*)d_in[0];
    const float* k_in = (const float*)d_in[1];
    const float* v_in = (const float*)d_in[2];
    const float* Qw_f = (const float*)d_in[3];
    const float* Kw_f = (const float*)d_in[4];
    const float* Vw_f = (const float*)d_in[5];
    float* out = (float*)d_out;

    const int Bb = 4, S = 2048, E = 1024;
    const size_t TOK = (size_t)Bb * S;       // 8192
    const size_t NTE = TOK * E;              // 8,388,608
    const size_t NW  = (size_t)E * E;        // 1,048,576

    unsigned short* ws = (unsigned short*)d_ws;
    unsigned short* Xq = ws;            // [8192,1024]
    unsigned short* Xk = Xq + NTE;
    unsigned short* Xv = Xk + NTE;
    unsigned short* Wq = Xv + NTE;      // [1024,1024]
    unsigned short* Wk = Wq + NW;
    unsigned short* Wv = Wk + NW;
    unsigned short* qb = Wv + NW;       // [8192,1024]
    unsigned short* kb = qb + NTE;
    unsigned short* vT = kb + NTE;      // [1024 e][8192 tok]
    unsigned short* Sc = vT + NTE;      // [4][2048][2048] exp-scores
    float* rowsum = (float*)(Sc + (size_t)Bb * S * S);  // [4][2048]

    // 1) all converts + rowsum zero, one dispatch
    {
        const long G = 3 * (long)(NTE / 4) + 3 * (long)(NW / 4) + (Bb * S / 4);
        cvt_all<<<(unsigned)(G / 256), 256, 0, stream>>>(
            q_in, k_in, v_in, Qw_f, Kw_f, Vw_f,
            Xq, Xk, Xv, Wq, Wk, Wv, rowsum);
    }

    // 2) all three projections, one dispatch (1536 blocks, 128^2 proven body)
    proj_kernel<<<dim3(TOK / BM, E / BN, 3), 256, 0, stream>>>(
        Xq, Wq, qb, Xk, Wk, kb, Wv, Xv, vT);

    // 3) P = exp(q k^T / 32) + fp32 rowsums (256 blocks, perfect packing)
    scores256_kernel<<<dim3(S / 256, S / 256, 4), 512, 0, stream>>>(
        qb, kb, Sc, rowsum);

    // 4) out = (P @ v) / rowsum  (128^2 body, 512 blocks, 4/CU)
    pv_kernel<<<dim3(S / BM, E / BN, 4), 256, 0, stream>>>(
        Sc, vT, out, rowsum);
}